// Round 20
// baseline (310.123 us; speedup 1.0000x reference)
//
#include <hip/hip_runtime.h>

typedef _Float16 half8 __attribute__((ext_vector_type(8)));
typedef float floatx4 __attribute__((ext_vector_type(4)));
typedef unsigned short ushort8v __attribute__((ext_vector_type(8)));

#define NS 8
#define CCH 32
#define GRDH_ROWS 288
#define CORR_N (136*136)
#define PCOPY2 ((size_t)(8*32*272*288))  // elems per parity copy (20,054,016)
#define NWG_GEMM 1024

#define LDSA_BYTES 20480                 // 160 rows (8n x 20) x 64 halfs (j-quarter), swizzled
#define LDSB_BYTES 20480                 // 32 superrows x 4 parities x 160 B, linear dest
#define LDS_TOTAL  (LDSA_BYTES + LDSB_BYTES)   // 40960 -> LDS allows 4/CU; VGPR caps at 3

// ---- workspace offsets (bytes) ----
#define OFF_NORMSQD  ((size_t)0)                   // 8 floats (written by k_sim)
#define OFF_YX       ((size_t)256)
#define OFF_PARTICAL ((size_t)512)                 // 8*17*17 floats
#define OFF_NSQP     ((size_t)0x4000)              // 8*288 floats (per-row norm partials)
#define OFF_CORR8    ((size_t)0x40000)             // 8*136*136 floats (per-chunk partials)
#define OFF_E        ((size_t)0x100000)            // 8*256*256 floats (2 MiB)
#define OFF_CSUMG    ((size_t)0x300000)            // 8*256*256 floats
#define OFF_GRDH     ((size_t)0x500000)            // 8*32*288*256 fp16 (ends 43.0 MB)
#define OFF_SATH     ((size_t)0x2A00000)           // 2 parity copies fp16 (ends 124.3 MB)
#define OFF_PARTIALS ((size_t)0x7800000)           // 1024*136*136 floats (ends 201.6 MB)

// Fused staging: y<8 -> grd part (n=y, padded row x), y>=8 -> sat part (m=y-8, row x).
__global__ __launch_bounds__(256) void k_stage(const float* __restrict__ grd,
                                               const float* __restrict__ sat,
                                               _Float16* __restrict__ grdh,
                                               float* __restrict__ csumg,
                                               float* __restrict__ nsq_part,
                                               _Float16* __restrict__ satp,
                                               float* __restrict__ E) {
    __shared__ float shA[8][256];
    __shared__ float wsum[4];
    __shared__ unsigned short ldsS[32][296];
    int part = blockIdx.y;
    int tid = threadIdx.x;
    union HU { _Float16 h; unsigned short u; };

    if (part < 8) {
        int n  = part;
        int Rg = blockIdx.x;       // 0..287 padded row
        int cb = tid >> 5;         // 0..7
        int col8 = (tid & 31) * 8;

        if (Rg < 16 || Rg >= 272) {
            ushort8v z = {0,0,0,0,0,0,0,0};
#pragma unroll
            for (int pass = 0; pass < 4; ++pass) {
                int c = pass*8 + cb;
                *(ushort8v*)(grdh + (((size_t)(n*CCH + c))*GRDH_ROWS + Rg)*256 + col8) = z;
            }
            if (tid == 0) nsq_part[n*288 + Rg] = 0.f;
            return;
        }
        int i = Rg - 16;
        float ssq = 0.f;
        float cs[8] = {};
#pragma unroll
        for (int pass = 0; pass < 4; ++pass) {
            int c = pass*8 + cb;
            const float* src = grd + (((size_t)(n*CCH + c))*256 + i)*256 + col8;
            float4 v0 = *(const float4*)src;
            float4 v1 = *(const float4*)(src + 4);
            float vv[8] = {v0.x, v0.y, v0.z, v0.w, v1.x, v1.y, v1.z, v1.w};
            ushort8v w;
#pragma unroll
            for (int j = 0; j < 8; ++j) {
                HU hu; hu.h = (_Float16)vv[j]; w[j] = hu.u;
                ssq += vv[j]*vv[j]; cs[j] += vv[j];
            }
            *(ushort8v*)(grdh + (((size_t)(n*CCH + c))*GRDH_ROWS + Rg)*256 + col8) = w;
        }
#pragma unroll
        for (int j = 0; j < 8; ++j) shA[cb][col8 + j] = cs[j];
        for (int o = 32; o; o >>= 1) ssq += __shfl_down(ssq, o, 64);
        if ((tid & 63) == 0) wsum[tid >> 6] = ssq;
        __syncthreads();
        float csum = 0.f;
#pragma unroll
        for (int q = 0; q < 8; ++q) csum += shA[q][tid];
        csumg[((size_t)n*256 + i)*256 + tid] = csum;
        if (tid == 0)
            nsq_part[n*288 + Rg] = wsum[0] + wsum[1] + wsum[2] + wsum[3];
    } else {
        if (blockIdx.x >= 256) return;
        int m = part - 8;
        int R = blockIdx.x + 8;    // padded row 8..263
        int i = R - 8;

        float vreg[32];
#pragma unroll
        for (int c = 0; c < CCH; ++c)
            vreg[c] = sat[(((size_t)(m*CCH + c))*256 + i)*256 + tid];

        float es = 0.f;
#pragma unroll
        for (int c = 0; c < CCH; ++c) es += vreg[c]*vreg[c];
        E[((size_t)m*256 + i)*256 + tid] = es;

#pragma unroll
        for (int c = 0; c < CCH; ++c) {
            HU h; h.h = (_Float16)vreg[c];
            ldsS[c][8 + tid] = h.u;
        }
#pragma unroll
        for (int z = 0; z < 5; ++z) {
            int idx = z*256 + tid;
            int c = idx / 40, o = idx - c*40;
            ldsS[c][(o < 8) ? o : (256 + o)] = 0;
        }
        __syncthreads();
#pragma unroll
        for (int it = 0; it < 9; ++it) {
            int chunk = it*256 + tid;
            int c = chunk / 72;
            int rest = chunk - c*72;
            int p = rest / 36, k = rest - p*36;
            ushort8v w;
#pragma unroll
            for (int j = 0; j < 8; ++j) w[j] = ldsS[c][8*k + p + j];
            *(ushort8v*)(satp + (size_t)p*PCOPY2 +
                         (((size_t)(m*CCH + c))*272 + R)*288 + 8*k) = w;
        }
    }
}

// all-pairs shifted correlation as MFMA GEMM, LDS-staged via global_load_lds.
// WG = (band 64) x (8-ch group 4) x (j-quarter 4) = 1024; K/WG = 4r x 8c x 64j.
// LDS 40 KB; __launch_bounds__(256,3) -> ~168-reg budget, 3 WGs/CU (12 waves).
// Fragments SINGLE-buffered (saves 40 regs; compiler pipelines the unrolled body).
// LDS A: [160 rows = 8n x 20][64 halfs], 16B chunks XOR-swizzled by (row & 7).
// LDS B: [32 superrows = 4r x 8m][4 parities x 160 B]; parity stride 160B == 40 dw
//        == 8 mod 32 banks; superrow 640B == 0 mod 32. Dest linear in chunk.
__global__ __launch_bounds__(256, 3) void k_gemm(const _Float16* __restrict__ grdh,
                                                 const _Float16* __restrict__ satp,
                                                 float* __restrict__ partials) {
    extern __shared__ char smem[];
    _Float16* ldsA = (_Float16*)smem;
    char*     ldsB = smem + LDSA_BYTES;

    const int wgid = blockIdx.x;        // 0..1023 = slice
    const int band = wgid >> 4;         // 0..63
    const int cgg  = (wgid >> 2) & 3;   // 8-channel group
    const int jq   = wgid & 3;          // j quarter (64 cols)
    const int r0   = 8 + band * 4;
    const int jb   = jq * 64;
    const int tid  = threadIdx.x;       // 0..255
    const int wave = tid >> 6;          // 0..3
    const int wr   = wave >> 1, wc = wave & 1;
    const int lane = tid & 63;
    const int lrow = lane & 15, lk = lane >> 4;

    int sBaseA[5];                      // LDS A row base (n*20 + 16 - dy)
    int baseB[5];                       // LDS B byte base
#pragma unroll
    for (int a = 0; a < 5; ++a) {
        int v = (wr*5 + a)*16 + lrow; if (v > 135) v = 135;
        int n = v / 17, dy = v % 17;
        sBaseA[a] = n*20 + 16 - dy;
    }
#pragma unroll
    for (int b = 0; b < 5; ++b) {
        int C = (wc*5 + b)*16 + lrow; if (C > 135) C = 135;
        int m = C / 17, dx = C % 17;
        int p = dx & 3, q = dx & ~3;
        baseB[b] = m*640 + p*160 + ((q + lk*8) << 1);
    }

    floatx4 acc[5][5] = {};
    half8 A0[5], B0[5];

#define LOADPH(Ax, Bx, PH) do { \
    const int r_ = (PH) >> 1, ch_ = (PH) & 1; \
    _Pragma("unroll") for (int a = 0; a < 5; ++a) { \
        int s_ = sBaseA[a] + r_; \
        int byte_ = (s_ << 7) + ((((ch_*4) + lk) ^ (s_ & 7)) << 4); \
        Ax[a] = *(const half8*)((const char*)ldsA + byte_); } \
    _Pragma("unroll") for (int b = 0; b < 5; ++b) { \
        int off_ = baseB[b] + r_*5120 + ch_*64; \
        union { unsigned long long u[2]; half8 v; } U_; \
        U_.u[0] = *(const unsigned long long*)(ldsB + off_); \
        U_.u[1] = *(const unsigned long long*)(ldsB + off_ + 8); \
        Bx[b] = U_.v; } \
} while (0)

#define MFMAS(Ax, Bx) do { \
    _Pragma("unroll") for (int a = 0; a < 5; ++a) \
    _Pragma("unroll") for (int b = 0; b < 5; ++b) \
        acc[a][b] = __builtin_amdgcn_mfma_f32_16x16x32_f16(Ax[a], Bx[b], acc[a][b], 0, 0, 0); \
} while (0)

    for (int g = 0; g < 8; ++g) {
        int cc = cgg*8 + g;
        __syncthreads();               // prev iteration's readers done
        // stage A: 1280 x 16B chunks (5/thread): row s (0..159) x 8 chunks,
        // XOR(s&7) pre-swizzled source within the j-quarter.
#pragma unroll
        for (int it = 0; it < 5; ++it) {
            int chunk = it*256 + tid;
            int s = chunk >> 3, k = chunk & 7;
            int n = s / 20, w = s - n*20;
            const _Float16* src = grdh +
                ((((size_t)(n*CCH + cc))*GRDH_ROWS + (r0 + w)) << 8) +
                jb + ((k ^ (s & 7)) << 3);
            __builtin_amdgcn_global_load_lds(src, ldsA + chunk*8, 16, 0, 0);
        }
        // stage B: 1280 x 16B chunks (5/thread): superrow (r*8+m) = 4p x 160B.
        // LDS parity p <- global copy (p&1) at +2*(p>>1) halfs. Dest linear.
#pragma unroll
        for (int it = 0; it < 5; ++it) {
            int chunk = it*256 + tid;
            int sr = chunk / 40;
            int rest = chunk - sr*40;
            int p = rest / 10, k = rest - p*10;
            const _Float16* src = satp + (size_t)(p & 1)*PCOPY2 +
                (((size_t)((sr & 7)*CCH + cc))*272 + (r0 + (sr >> 3)))*288 +
                jb + 2*(p >> 1) + k*8;
            __builtin_amdgcn_global_load_lds(src,
                (_Float16*)(ldsB + chunk*16), 16, 0, 0);
        }
        asm volatile("s_waitcnt vmcnt(0)" ::: "memory");
        __syncthreads();               // all staging visible

#pragma unroll
        for (int ph = 0; ph < 8; ++ph) {
            LOADPH(A0, B0, ph);
            MFMAS(A0, B0);
        }
    }
#undef LOADPH
#undef MFMAS

    // Coalesced C-write: stage 68-row halves in (dead) LDS, then float4 stores.
    float* myp = partials + (size_t)wgid * CORR_N;
    float* ldsOut = (float*)smem;      // 40960 >= 68*136*4 = 36992
#pragma unroll
    for (int h = 0; h < 2; ++h) {
        __syncthreads();
#pragma unroll
        for (int a = 0; a < 5; ++a) {
            int rowg0 = (wr*5 + a)*16 + lk*4;
#pragma unroll
            for (int b = 0; b < 5; ++b) {
                int colg = (wc*5 + b)*16 + lrow;
                if (colg < 136) {
#pragma unroll
                    for (int v = 0; v < 4; ++v) {
                        int rl = rowg0 + v - h*68;
                        if (rl >= 0 && rl < 68)
                            ldsOut[rl*136 + colg] = acc[a][b][v];
                    }
                }
            }
        }
        __syncthreads();
#pragma unroll
        for (int it = 0; it < 10; ++it) {
            int idx = it*256 + tid;
            if (idx < 2312) {          // 68 rows x 34 float4
                int row = idx / 34, c4 = idx - row*34;
                *(float4*)(myp + (size_t)(h*68 + row)*136 + c4*4) =
                    *(const float4*)(ldsOut + row*136 + c4*4);
            }
        }
    }
}

// partials (1024 slices) -> 8 chunk-partials (no atomics, no init needed)
__global__ __launch_bounds__(256) void k_reduce(const float* __restrict__ partials,
                                                float* __restrict__ corr8) {
    int t = blockIdx.x * 256 + threadIdx.x;
    if (t >= CORR_N) return;
    int w0 = blockIdx.y * 128;
    float s = 0.f;
    for (int w = w0; w < w0 + 128; ++w) s += partials[(size_t)w*CORR_N + t];
    corr8[(size_t)blockIdx.y*CORR_N + t] = s;
}

__global__ __launch_bounds__(256) void k_part(const float* __restrict__ E,
                                              float* __restrict__ partical) {
    int dy = blockIdx.x;   // 0..16
    int m  = blockIdx.y;
    int j  = threadIdx.x;
    int lo = dy - 8; if (lo < 0) lo = 0;
    int hi = dy + 248; if (hi > 256) hi = 256;
    float s = 0.f;
    for (int i = lo; i < hi; ++i) s += E[((size_t)m*256 + i)*256 + j];
    __shared__ float sh[256];
    sh[j] = s;
    __syncthreads();
    if (j < 17) {
        int lo2 = j - 8; if (lo2 < 0) lo2 = 0;
        int hi2 = j + 248; if (hi2 > 256) hi2 = 256;
        float t = 0.f;
        for (int x = lo2; x < hi2; ++x) t += sh[x];
        partical[(m*17 + dy)*17 + j] = t;
    }
}

__global__ __launch_bounds__(64) void k_sim(const float* __restrict__ corr8,
                                            const float* __restrict__ partical,
                                            const float* __restrict__ nsq_part,
                                            float* __restrict__ out,
                                            int* __restrict__ yx,
                                            float* __restrict__ normsqd) {
    int m = blockIdx.x >> 3, n = blockIdx.x & 7;
    int lane = threadIdx.x;
    float ns = 0.f;
    for (int r = lane; r < 288; r += 64) ns += nsq_part[n*288 + r];
    for (int o = 32; o; o >>= 1) ns += __shfl_down(ns, o, 64);
    ns = __shfl(ns, 0, 64);
    float Ng = sqrtf(ns);

    float bv = -1e30f; int bpos = 0;
    for (int t = 0; t < 5; ++t) {
        int pos = t*64 + lane;
        if (pos < 289) {
            int dy = pos / 17, dx = pos % 17;
            int idx = (n*17 + dy)*136 + (m*17 + dx);
            float cv = 0.f;
#pragma unroll
            for (int y = 0; y < 8; ++y) cv += corr8[(size_t)y*CORR_N + idx];
            float denom = fmaxf(Ng * sqrtf(partical[(m*17 + dy)*17 + dx]), 1e-12f);
            float val = cv / denom;
            if (val > bv) { bv = val; bpos = pos; }  // strict > keeps first index
        }
    }
    for (int o = 32; o; o >>= 1) {
        float ov = __shfl_xor(bv, o, 64);
        int   op = __shfl_xor(bpos, o, 64);
        if (ov > bv || (ov == bv && op < bpos)) { bv = ov; bpos = op; }
    }
    if (lane == 0) {
        out[m*8 + n] = bv;
        if (m == n) { yx[m] = bpos; normsqd[m] = ns; }
    }
}

__global__ __launch_bounds__(256) void k_mask(const float* __restrict__ csumg,
                                              const float* __restrict__ normsqd,
                                              const int* __restrict__ yx,
                                              float* __restrict__ out) {
    int i = blockIdx.x, m = blockIdx.y, j = threadIdx.x;
    int pos = yx[m];
    int y = pos / 17, x = pos % 17;
    float Ng = sqrtf(normsqd[m]);
    int a = i + 8 - y, b = j + 8 - x;
    float val = 0.f;
    if (a >= 0 && a < 256 && b >= 0 && b < 256)
        val = (fabsf(csumg[((size_t)m*256 + a)*256 + b]) > 1e-6f*Ng) ? 1.f : 0.f;
    out[64 + ((size_t)m*256 + i)*256 + j] = val;
}

extern "C" void kernel_launch(void* const* d_in, const int* in_sizes, int n_in,
                              void* d_out, int out_size, void* d_ws, size_t ws_size,
                              hipStream_t stream) {
    const float* grd = (const float*)d_in[0];
    const float* sat = (const float*)d_in[1];
    float* out = (float*)d_out;
    char* ws = (char*)d_ws;

    float*    normsqd  = (float*)(ws + OFF_NORMSQD);
    int*      yx       = (int*)  (ws + OFF_YX);
    float*    partical = (float*)(ws + OFF_PARTICAL);
    float*    nsq_part = (float*)(ws + OFF_NSQP);
    float*    corr8    = (float*)(ws + OFF_CORR8);
    float*    E        = (float*)(ws + OFF_E);
    float*    csumg    = (float*)(ws + OFF_CSUMG);
    _Float16* grdh     = (_Float16*)(ws + OFF_GRDH);
    _Float16* satp     = (_Float16*)(ws + OFF_SATH);
    float*    partials = (float*)(ws + OFF_PARTIALS);

    hipFuncSetAttribute(reinterpret_cast<const void*>(k_gemm),
                        hipFuncAttributeMaxDynamicSharedMemorySize, LDS_TOTAL);

    k_stage<<<dim3(288, 16), 256, 0, stream>>>(grd, sat, grdh, csumg, nsq_part, satp, E);
    k_gemm<<<NWG_GEMM, 256, LDS_TOTAL, stream>>>(grdh, satp, partials);
    k_reduce<<<dim3((CORR_N + 255)/256, 8), 256, 0, stream>>>(partials, corr8);
    k_part<<<dim3(17, 8), 256, 0, stream>>>(E, partical);
    k_sim<<<64, 64, 0, stream>>>(corr8, partical, nsq_part, out, yx, normsqd);
    k_mask<<<dim3(256, 8), 256, 0, stream>>>(csumg, normsqd, yx, out);
}

// Round 21
// 234.773 us; speedup vs baseline: 1.3209x; 1.3209x over previous
//
#include <hip/hip_runtime.h>

typedef _Float16 half8 __attribute__((ext_vector_type(8)));
typedef float floatx4 __attribute__((ext_vector_type(4)));
typedef unsigned short ushort8v __attribute__((ext_vector_type(8)));

#define NS 8
#define CCH 32
#define GRDH_ROWS 288
#define CORR_N (136*136)
#define PCOPY2 ((size_t)(8*32*272*288))  // elems per parity copy (20,054,016)
#define NWG_GEMM 512

#define LDSA_BYTES 40960                 // 160 rows (8n x 20) x 128 halfs (j-half), swizzled
#define LDSB_BYTES 36864                 // 32 superrows x 4 parities x 288 B, linear dest
#define LDS_TOTAL  (LDSA_BYTES + LDSB_BYTES)   // 77824 -> 2 WGs/CU

// ---- workspace offsets (bytes) ----
#define OFF_NORMSQD  ((size_t)0)                   // 8 floats (written by k_sim)
#define OFF_YX       ((size_t)256)
#define OFF_PARTICAL ((size_t)512)                 // 8*17*17 floats
#define OFF_NSQP     ((size_t)0x4000)              // 8*288 floats (per-row norm partials)
#define OFF_CORR8    ((size_t)0x40000)             // 8*136*136 floats (per-chunk partials)
#define OFF_E        ((size_t)0x100000)            // 8*256*256 floats (2 MiB)
#define OFF_CSUMG    ((size_t)0x300000)            // 8*256*256 floats
#define OFF_GRDH     ((size_t)0x500000)            // 8*32*288*256 fp16
#define OFF_SATH     ((size_t)0x2A00000)           // 2 parity copies fp16 (80.2 MB)
#define OFF_PARTIALS ((size_t)0xBB00000)           // 512*136*136 floats

// Fused staging: y<8 -> grd part (n=y, padded row x), y>=8 -> sat part (m=y-8, row x).
// Both halves run concurrently; no atomics anywhere.
__global__ __launch_bounds__(256) void k_stage(const float* __restrict__ grd,
                                               const float* __restrict__ sat,
                                               _Float16* __restrict__ grdh,
                                               float* __restrict__ csumg,
                                               float* __restrict__ nsq_part,
                                               _Float16* __restrict__ satp,
                                               float* __restrict__ E) {
    __shared__ float shA[8][256];
    __shared__ float wsum[4];
    __shared__ unsigned short ldsS[32][296];
    int part = blockIdx.y;
    int tid = threadIdx.x;
    union HU { _Float16 h; unsigned short u; };

    if (part < 8) {
        // ---- grd -> grdh + csumg + nsq_part ----
        int n  = part;
        int Rg = blockIdx.x;       // 0..287 padded row
        int cb = tid >> 5;         // 0..7
        int col8 = (tid & 31) * 8;

        if (Rg < 16 || Rg >= 272) {
            ushort8v z = {0,0,0,0,0,0,0,0};
#pragma unroll
            for (int pass = 0; pass < 4; ++pass) {
                int c = pass*8 + cb;
                *(ushort8v*)(grdh + (((size_t)(n*CCH + c))*GRDH_ROWS + Rg)*256 + col8) = z;
            }
            if (tid == 0) nsq_part[n*288 + Rg] = 0.f;
            return;
        }
        int i = Rg - 16;
        float ssq = 0.f;
        float cs[8] = {};
#pragma unroll
        for (int pass = 0; pass < 4; ++pass) {
            int c = pass*8 + cb;
            const float* src = grd + (((size_t)(n*CCH + c))*256 + i)*256 + col8;
            float4 v0 = *(const float4*)src;
            float4 v1 = *(const float4*)(src + 4);
            float vv[8] = {v0.x, v0.y, v0.z, v0.w, v1.x, v1.y, v1.z, v1.w};
            ushort8v w;
#pragma unroll
            for (int j = 0; j < 8; ++j) {
                HU hu; hu.h = (_Float16)vv[j]; w[j] = hu.u;
                ssq += vv[j]*vv[j]; cs[j] += vv[j];
            }
            *(ushort8v*)(grdh + (((size_t)(n*CCH + c))*GRDH_ROWS + Rg)*256 + col8) = w;
        }
#pragma unroll
        for (int j = 0; j < 8; ++j) shA[cb][col8 + j] = cs[j];
        for (int o = 32; o; o >>= 1) ssq += __shfl_down(ssq, o, 64);
        if ((tid & 63) == 0) wsum[tid >> 6] = ssq;
        __syncthreads();
        float csum = 0.f;
#pragma unroll
        for (int q = 0; q < 8; ++q) csum += shA[q][tid];
        csumg[((size_t)n*256 + i)*256 + tid] = csum;
        if (tid == 0)
            nsq_part[n*288 + Rg] = wsum[0] + wsum[1] + wsum[2] + wsum[3];
    } else {
        // ---- sat -> 2 parity copies + E ----
        if (blockIdx.x >= 256) return;
        int m = part - 8;
        int R = blockIdx.x + 8;    // padded row 8..263
        int i = R - 8;

        float vreg[32];
#pragma unroll
        for (int c = 0; c < CCH; ++c)
            vreg[c] = sat[(((size_t)(m*CCH + c))*256 + i)*256 + tid];

        float es = 0.f;
#pragma unroll
        for (int c = 0; c < CCH; ++c) es += vreg[c]*vreg[c];
        E[((size_t)m*256 + i)*256 + tid] = es;

#pragma unroll
        for (int c = 0; c < CCH; ++c) {
            HU h; h.h = (_Float16)vreg[c];
            ldsS[c][8 + tid] = h.u;
        }
        // zero pads: cols 0..7 and 264..295 (40 per row, 1280 total, 5/thread)
#pragma unroll
        for (int z = 0; z < 5; ++z) {
            int idx = z*256 + tid;
            int c = idx / 40, o = idx - c*40;
            ldsS[c][(o < 8) ? o : (256 + o)] = 0;
        }
        __syncthreads();
        // 2304 ushort8 chunks: (c 32) x (p 2) x (k 36); 9 per thread
#pragma unroll
        for (int it = 0; it < 9; ++it) {
            int chunk = it*256 + tid;
            int c = chunk / 72;
            int rest = chunk - c*72;
            int p = rest / 36, k = rest - p*36;
            ushort8v w;
#pragma unroll
            for (int j = 0; j < 8; ++j) w[j] = ldsS[c][8*k + p + j];
            *(ushort8v*)(satp + (size_t)p*PCOPY2 +
                         (((size_t)(m*CCH + c))*272 + R)*288 + 8*k) = w;
        }
    }
}

// all-pairs shifted correlation as MFMA GEMM, LDS-staged via global_load_lds.
// (the verified 128-131 us round-12/16/17/19 version, unchanged)
__global__ __launch_bounds__(256, 2) void k_gemm(const _Float16* __restrict__ grdh,
                                                 const _Float16* __restrict__ satp,
                                                 float* __restrict__ partials) {
    extern __shared__ char smem[];
    _Float16* ldsA = (_Float16*)smem;
    char*     ldsB = smem + LDSA_BYTES;

    const int wgid = blockIdx.x;        // 0..511 = slice
    const int band = wgid >> 3;         // 0..63
    const int cgg  = (wgid >> 1) & 3;   // 8-channel group
    const int jh   = wgid & 1;          // j half (128 cols)
    const int r0   = 8 + band * 4;
    const int jb   = jh * 128;
    const int tid  = threadIdx.x;       // 0..255
    const int wave = tid >> 6;          // 0..3
    const int wr   = wave >> 1, wc = wave & 1;
    const int lane = tid & 63;
    const int lrow = lane & 15, lk = lane >> 4;

    int sBaseA[5];                      // LDS A row base (n*20 + 16 - dy)
    int baseB[5];                       // LDS B byte base
#pragma unroll
    for (int a = 0; a < 5; ++a) {
        int v = (wr*5 + a)*16 + lrow; if (v > 135) v = 135;
        int n = v / 17, dy = v % 17;
        sBaseA[a] = n*20 + 16 - dy;
    }
#pragma unroll
    for (int b = 0; b < 5; ++b) {
        int C = (wc*5 + b)*16 + lrow; if (C > 135) C = 135;
        int m = C / 17, dx = C % 17;
        int p = dx & 3, q = dx & ~3;
        baseB[b] = m*1152 + p*288 + ((q + lk*8) << 1);
    }

    floatx4 acc[5][5] = {};
    half8 A0[5], A1[5], B0[5], B1[5];

#define LOADPH(Ax, Bx, PH) do { \
    const int r_ = (PH) >> 2, ch_ = (PH) & 3; \
    _Pragma("unroll") for (int a = 0; a < 5; ++a) { \
        int s_ = sBaseA[a] + r_; \
        int byte_ = (s_ << 8) + ((((ch_*4) + lk) ^ (s_ & 15)) << 4); \
        Ax[a] = *(const half8*)((const char*)ldsA + byte_); } \
    _Pragma("unroll") for (int b = 0; b < 5; ++b) { \
        int off_ = baseB[b] + r_*9216 + ch_*64; \
        union { unsigned long long u[2]; half8 v; } U_; \
        U_.u[0] = *(const unsigned long long*)(ldsB + off_); \
        U_.u[1] = *(const unsigned long long*)(ldsB + off_ + 8); \
        Bx[b] = U_.v; } \
} while (0)

#define MFMAS(Ax, Bx) do { \
    _Pragma("unroll") for (int a = 0; a < 5; ++a) \
    _Pragma("unroll") for (int b = 0; b < 5; ++b) \
        acc[a][b] = __builtin_amdgcn_mfma_f32_16x16x32_f16(Ax[a], Bx[b], acc[a][b], 0, 0, 0); \
} while (0)

    for (int g = 0; g < 8; ++g) {
        int cc = cgg*8 + g;
        __syncthreads();               // prev iteration's readers done
#pragma unroll
        for (int it = 0; it < 10; ++it) {
            int chunk = it*256 + tid;
            int s = chunk >> 4, k = chunk & 15;
            int n = s / 20, w = s - n*20;
            const _Float16* src = grdh +
                ((((size_t)(n*CCH + cc))*GRDH_ROWS + (r0 + w)) << 8) +
                jb + ((k ^ (s & 15)) << 3);
            __builtin_amdgcn_global_load_lds(src, ldsA + chunk*8, 16, 0, 0);
        }
#pragma unroll
        for (int it = 0; it < 9; ++it) {
            int chunk = it*256 + tid;
            int sr = chunk / 72;
            int rest = chunk - sr*72;
            int p = rest / 18, k = rest - p*18;
            const _Float16* src = satp + (size_t)(p & 1)*PCOPY2 +
                (((size_t)((sr & 7)*CCH + cc))*272 + (r0 + (sr >> 3)))*288 +
                jb + 2*(p >> 1) + k*8;
            __builtin_amdgcn_global_load_lds(src,
                (_Float16*)(ldsB + chunk*16), 16, 0, 0);
        }
        asm volatile("s_waitcnt vmcnt(0)" ::: "memory");
        __syncthreads();               // all staging visible

        LOADPH(A0, B0, 0);
#pragma unroll
        for (int ph = 0; ph < 16; ++ph) {
            if ((ph & 1) == 0) {
                if (ph < 15) LOADPH(A1, B1, ph + 1);
                MFMAS(A0, B0);
            } else {
                if (ph < 15) LOADPH(A0, B0, ph + 1);
                MFMAS(A1, B1);
            }
        }
    }
#undef LOADPH
#undef MFMAS

    // Coalesced C-write: stage 68-row halves in (dead) ldsA, then float4 stores.
    float* myp = partials + (size_t)wgid * CORR_N;
    float* ldsOut = (float*)ldsA;      // 40960 >= 68*136*4 = 36992
#pragma unroll
    for (int h = 0; h < 2; ++h) {
        __syncthreads();
#pragma unroll
        for (int a = 0; a < 5; ++a) {
            int rowg0 = (wr*5 + a)*16 + lk*4;
#pragma unroll
            for (int b = 0; b < 5; ++b) {
                int colg = (wc*5 + b)*16 + lrow;
                if (colg < 136) {
#pragma unroll
                    for (int v = 0; v < 4; ++v) {
                        int rl = rowg0 + v - h*68;
                        if (rl >= 0 && rl < 68)
                            ldsOut[rl*136 + colg] = acc[a][b][v];
                    }
                }
            }
        }
        __syncthreads();
#pragma unroll
        for (int it = 0; it < 10; ++it) {
            int idx = it*256 + tid;
            if (idx < 2312) {          // 68 rows x 34 float4
                int row = idx / 34, c4 = idx - row*34;
                *(float4*)(myp + (size_t)(h*68 + row)*136 + c4*4) =
                    *(const float4*)(ldsOut + row*136 + c4*4);
            }
        }
    }
}

// partials (512 slices) -> 8 chunk-partials (no atomics, no init needed)
__global__ __launch_bounds__(256) void k_reduce(const float* __restrict__ partials,
                                                float* __restrict__ corr8) {
    int t = blockIdx.x * 256 + threadIdx.x;
    if (t >= CORR_N) return;
    int w0 = blockIdx.y * 64;
    float s = 0.f;
    for (int w = w0; w < w0 + 64; ++w) s += partials[(size_t)w*CORR_N + t];
    corr8[(size_t)blockIdx.y*CORR_N + t] = s;
}

__global__ __launch_bounds__(256) void k_part(const float* __restrict__ E,
                                              float* __restrict__ partical) {
    int dy = blockIdx.x;   // 0..16
    int m  = blockIdx.y;
    int j  = threadIdx.x;
    int lo = dy - 8; if (lo < 0) lo = 0;
    int hi = dy + 248; if (hi > 256) hi = 256;
    float s = 0.f;
    for (int i = lo; i < hi; ++i) s += E[((size_t)m*256 + i)*256 + j];
    __shared__ float sh[256];
    sh[j] = s;
    __syncthreads();
    if (j < 17) {
        int lo2 = j - 8; if (lo2 < 0) lo2 = 0;
        int hi2 = j + 248; if (hi2 > 256) hi2 = 256;
        float t = 0.f;
        for (int x = lo2; x < hi2; ++x) t += sh[x];
        partical[(m*17 + dy)*17 + j] = t;
    }
}

__global__ __launch_bounds__(64) void k_sim(const float* __restrict__ corr8,
                                            const float* __restrict__ partical,
                                            const float* __restrict__ nsq_part,
                                            float* __restrict__ out,
                                            int* __restrict__ yx,
                                            float* __restrict__ normsqd) {
    int m = blockIdx.x >> 3, n = blockIdx.x & 7;
    int lane = threadIdx.x;
    // Ng from per-row partials (288 values)
    float ns = 0.f;
    for (int r = lane; r < 288; r += 64) ns += nsq_part[n*288 + r];
    for (int o = 32; o; o >>= 1) ns += __shfl_down(ns, o, 64);
    ns = __shfl(ns, 0, 64);
    float Ng = sqrtf(ns);

    float bv = -1e30f; int bpos = 0;
    for (int t = 0; t < 5; ++t) {
        int pos = t*64 + lane;
        if (pos < 289) {
            int dy = pos / 17, dx = pos % 17;
            int idx = (n*17 + dy)*136 + (m*17 + dx);
            float cv = 0.f;
#pragma unroll
            for (int y = 0; y < 8; ++y) cv += corr8[(size_t)y*CORR_N + idx];
            float denom = fmaxf(Ng * sqrtf(partical[(m*17 + dy)*17 + dx]), 1e-12f);
            float val = cv / denom;
            if (val > bv) { bv = val; bpos = pos; }  // strict > keeps first index
        }
    }
    for (int o = 32; o; o >>= 1) {
        float ov = __shfl_xor(bv, o, 64);
        int   op = __shfl_xor(bpos, o, 64);
        if (ov > bv || (ov == bv && op < bpos)) { bv = ov; bpos = op; }
    }
    if (lane == 0) {
        out[m*8 + n] = bv;
        if (m == n) { yx[m] = bpos; normsqd[m] = ns; }
    }
}

__global__ __launch_bounds__(256) void k_mask(const float* __restrict__ csumg,
                                              const float* __restrict__ normsqd,
                                              const int* __restrict__ yx,
                                              float* __restrict__ out) {
    int i = blockIdx.x, m = blockIdx.y, j = threadIdx.x;
    int pos = yx[m];
    int y = pos / 17, x = pos % 17;
    float Ng = sqrtf(normsqd[m]);
    int a = i + 8 - y, b = j + 8 - x;
    float val = 0.f;
    if (a >= 0 && a < 256 && b >= 0 && b < 256)
        val = (fabsf(csumg[((size_t)m*256 + a)*256 + b]) > 1e-6f*Ng) ? 1.f : 0.f;
    out[64 + ((size_t)m*256 + i)*256 + j] = val;
}

extern "C" void kernel_launch(void* const* d_in, const int* in_sizes, int n_in,
                              void* d_out, int out_size, void* d_ws, size_t ws_size,
                              hipStream_t stream) {
    const float* grd = (const float*)d_in[0];
    const float* sat = (const float*)d_in[1];
    float* out = (float*)d_out;
    char* ws = (char*)d_ws;

    float*    normsqd  = (float*)(ws + OFF_NORMSQD);
    int*      yx       = (int*)  (ws + OFF_YX);
    float*    partical = (float*)(ws + OFF_PARTICAL);
    float*    nsq_part = (float*)(ws + OFF_NSQP);
    float*    corr8    = (float*)(ws + OFF_CORR8);
    float*    E        = (float*)(ws + OFF_E);
    float*    csumg    = (float*)(ws + OFF_CSUMG);
    _Float16* grdh     = (_Float16*)(ws + OFF_GRDH);
    _Float16* satp     = (_Float16*)(ws + OFF_SATH);
    float*    partials = (float*)(ws + OFF_PARTIALS);

    hipFuncSetAttribute(reinterpret_cast<const void*>(k_gemm),
                        hipFuncAttributeMaxDynamicSharedMemorySize, LDS_TOTAL);

    k_stage<<<dim3(288, 16), 256, 0, stream>>>(grd, sat, grdh, csumg, nsq_part, satp, E);
    k_gemm<<<NWG_GEMM, 256, LDS_TOTAL, stream>>>(grdh, satp, partials);
    k_reduce<<<dim3((CORR_N + 255)/256, 8), 256, 0, stream>>>(partials, corr8);
    k_part<<<dim3(17, 8), 256, 0, stream>>>(E, partical);
    k_sim<<<64, 64, 0, stream>>>(corr8, partical, nsq_part, out, yx, normsqd);
    k_mask<<<dim3(256, 8), 256, 0, stream>>>(csumg, normsqd, yx, out);
}

// Round 22
// 231.839 us; speedup vs baseline: 1.3377x; 1.0127x over previous
//
#include <hip/hip_runtime.h>

typedef _Float16 half8 __attribute__((ext_vector_type(8)));
typedef float floatx4 __attribute__((ext_vector_type(4)));
typedef unsigned short ushort8v __attribute__((ext_vector_type(8)));

#define NS 8
#define CCH 32
#define GRDH_ROWS 288
#define CORR_N (136*136)
#define PCOPY2 ((size_t)(8*32*272*288))  // elems per parity copy (20,054,016)
#define NWG_GEMM 512

#define LDSA_BYTES 40960                 // 160 rows (8n x 20) x 128 halfs (j-half), swizzled
#define LDSB_BYTES 36864                 // 32 superrows x 4 parities x 288 B, linear dest
#define LDS_TOTAL  (LDSA_BYTES + LDSB_BYTES)   // 77824 -> 2 WGs/CU

// ---- workspace offsets (bytes) ----
#define OFF_NORMSQD  ((size_t)0)                   // 8 floats (written by k_sim)
#define OFF_YX       ((size_t)256)
#define OFF_PARTICAL ((size_t)512)                 // 8*17*17 floats
#define OFF_NSQP     ((size_t)0x4000)              // 8*288 floats (per-row norm partials)
#define OFF_CORR8    ((size_t)0x40000)             // 8*136*136 floats (per-chunk partials)
#define OFF_E        ((size_t)0x100000)            // 8*256*256 floats (2 MiB)
#define OFF_CSUMG    ((size_t)0x300000)            // 8*256*256 floats
#define OFF_GRDH     ((size_t)0x500000)            // 8*32*288*256 fp16
#define OFF_SATH     ((size_t)0x2A00000)           // 2 parity copies fp16 (80.2 MB)
#define OFF_PARTIALS ((size_t)0xBB00000)           // 512*136*136 floats

// Fused staging: y<8 -> grd part (n=y, padded row x), y>=8 -> sat part (m=y-8, row x).
// Both halves run concurrently; no atomics anywhere.
__global__ __launch_bounds__(256) void k_stage(const float* __restrict__ grd,
                                               const float* __restrict__ sat,
                                               _Float16* __restrict__ grdh,
                                               float* __restrict__ csumg,
                                               float* __restrict__ nsq_part,
                                               _Float16* __restrict__ satp,
                                               float* __restrict__ E) {
    __shared__ float shA[8][256];
    __shared__ float wsum[4];
    __shared__ unsigned short ldsS[32][296];
    int part = blockIdx.y;
    int tid = threadIdx.x;
    union HU { _Float16 h; unsigned short u; };

    if (part < 8) {
        // ---- grd -> grdh + csumg + nsq_part ----
        int n  = part;
        int Rg = blockIdx.x;       // 0..287 padded row
        int cb = tid >> 5;         // 0..7
        int col8 = (tid & 31) * 8;

        if (Rg < 16 || Rg >= 272) {
            ushort8v z = {0,0,0,0,0,0,0,0};
#pragma unroll
            for (int pass = 0; pass < 4; ++pass) {
                int c = pass*8 + cb;
                *(ushort8v*)(grdh + (((size_t)(n*CCH + c))*GRDH_ROWS + Rg)*256 + col8) = z;
            }
            if (tid == 0) nsq_part[n*288 + Rg] = 0.f;
            return;
        }
        int i = Rg - 16;
        float ssq = 0.f;
        float cs[8] = {};
#pragma unroll
        for (int pass = 0; pass < 4; ++pass) {
            int c = pass*8 + cb;
            const float* src = grd + (((size_t)(n*CCH + c))*256 + i)*256 + col8;
            float4 v0 = *(const float4*)src;
            float4 v1 = *(const float4*)(src + 4);
            float vv[8] = {v0.x, v0.y, v0.z, v0.w, v1.x, v1.y, v1.z, v1.w};
            ushort8v w;
#pragma unroll
            for (int j = 0; j < 8; ++j) {
                HU hu; hu.h = (_Float16)vv[j]; w[j] = hu.u;
                ssq += vv[j]*vv[j]; cs[j] += vv[j];
            }
            *(ushort8v*)(grdh + (((size_t)(n*CCH + c))*GRDH_ROWS + Rg)*256 + col8) = w;
        }
#pragma unroll
        for (int j = 0; j < 8; ++j) shA[cb][col8 + j] = cs[j];
        for (int o = 32; o; o >>= 1) ssq += __shfl_down(ssq, o, 64);
        if ((tid & 63) == 0) wsum[tid >> 6] = ssq;
        __syncthreads();
        float csum = 0.f;
#pragma unroll
        for (int q = 0; q < 8; ++q) csum += shA[q][tid];
        csumg[((size_t)n*256 + i)*256 + tid] = csum;
        if (tid == 0)
            nsq_part[n*288 + Rg] = wsum[0] + wsum[1] + wsum[2] + wsum[3];
    } else {
        // ---- sat -> 2 parity copies + E ----
        if (blockIdx.x >= 256) return;
        int m = part - 8;
        int R = blockIdx.x + 8;    // padded row 8..263
        int i = R - 8;

        float vreg[32];
#pragma unroll
        for (int c = 0; c < CCH; ++c)
            vreg[c] = sat[(((size_t)(m*CCH + c))*256 + i)*256 + tid];

        float es = 0.f;
#pragma unroll
        for (int c = 0; c < CCH; ++c) es += vreg[c]*vreg[c];
        E[((size_t)m*256 + i)*256 + tid] = es;

#pragma unroll
        for (int c = 0; c < CCH; ++c) {
            HU h; h.h = (_Float16)vreg[c];
            ldsS[c][8 + tid] = h.u;
        }
        // zero pads: cols 0..7 and 264..295 (40 per row, 1280 total, 5/thread)
#pragma unroll
        for (int z = 0; z < 5; ++z) {
            int idx = z*256 + tid;
            int c = idx / 40, o = idx - c*40;
            ldsS[c][(o < 8) ? o : (256 + o)] = 0;
        }
        __syncthreads();
        // 2304 ushort8 chunks: (c 32) x (p 2) x (k 36); 9 per thread
#pragma unroll
        for (int it = 0; it < 9; ++it) {
            int chunk = it*256 + tid;
            int c = chunk / 72;
            int rest = chunk - c*72;
            int p = rest / 36, k = rest - p*36;
            ushort8v w;
#pragma unroll
            for (int j = 0; j < 8; ++j) w[j] = ldsS[c][8*k + p + j];
            *(ushort8v*)(satp + (size_t)p*PCOPY2 +
                         (((size_t)(m*CCH + c))*272 + R)*288 + 8*k) = w;
        }
    }
}

// all-pairs shifted correlation as MFMA GEMM, LDS-staged via global_load_lds.
// Verified 131 us structure + T5 s_setprio around the compute phase:
// 2 independent WGs/CU at uncorrelated phases -> scheduler prefers MFMA waves
// over the other WG's staging waves (attn-like regime, m191).
__global__ __launch_bounds__(256, 2) void k_gemm(const _Float16* __restrict__ grdh,
                                                 const _Float16* __restrict__ satp,
                                                 float* __restrict__ partials) {
    extern __shared__ char smem[];
    _Float16* ldsA = (_Float16*)smem;
    char*     ldsB = smem + LDSA_BYTES;

    const int wgid = blockIdx.x;        // 0..511 = slice
    const int band = wgid >> 3;         // 0..63
    const int cgg  = (wgid >> 1) & 3;   // 8-channel group
    const int jh   = wgid & 1;          // j half (128 cols)
    const int r0   = 8 + band * 4;
    const int jb   = jh * 128;
    const int tid  = threadIdx.x;       // 0..255
    const int wave = tid >> 6;          // 0..3
    const int wr   = wave >> 1, wc = wave & 1;
    const int lane = tid & 63;
    const int lrow = lane & 15, lk = lane >> 4;

    int sBaseA[5];                      // LDS A row base (n*20 + 16 - dy)
    int baseB[5];                       // LDS B byte base
#pragma unroll
    for (int a = 0; a < 5; ++a) {
        int v = (wr*5 + a)*16 + lrow; if (v > 135) v = 135;
        int n = v / 17, dy = v % 17;
        sBaseA[a] = n*20 + 16 - dy;
    }
#pragma unroll
    for (int b = 0; b < 5; ++b) {
        int C = (wc*5 + b)*16 + lrow; if (C > 135) C = 135;
        int m = C / 17, dx = C % 17;
        int p = dx & 3, q = dx & ~3;
        baseB[b] = m*1152 + p*288 + ((q + lk*8) << 1);
    }

    floatx4 acc[5][5] = {};
    half8 A0[5], A1[5], B0[5], B1[5];

#define LOADPH(Ax, Bx, PH) do { \
    const int r_ = (PH) >> 2, ch_ = (PH) & 3; \
    _Pragma("unroll") for (int a = 0; a < 5; ++a) { \
        int s_ = sBaseA[a] + r_; \
        int byte_ = (s_ << 8) + ((((ch_*4) + lk) ^ (s_ & 15)) << 4); \
        Ax[a] = *(const half8*)((const char*)ldsA + byte_); } \
    _Pragma("unroll") for (int b = 0; b < 5; ++b) { \
        int off_ = baseB[b] + r_*9216 + ch_*64; \
        union { unsigned long long u[2]; half8 v; } U_; \
        U_.u[0] = *(const unsigned long long*)(ldsB + off_); \
        U_.u[1] = *(const unsigned long long*)(ldsB + off_ + 8); \
        Bx[b] = U_.v; } \
} while (0)

#define MFMAS(Ax, Bx) do { \
    _Pragma("unroll") for (int a = 0; a < 5; ++a) \
    _Pragma("unroll") for (int b = 0; b < 5; ++b) \
        acc[a][b] = __builtin_amdgcn_mfma_f32_16x16x32_f16(Ax[a], Bx[b], acc[a][b], 0, 0, 0); \
} while (0)

    for (int g = 0; g < 8; ++g) {
        int cc = cgg*8 + g;
        __syncthreads();               // prev iteration's readers done
#pragma unroll
        for (int it = 0; it < 10; ++it) {
            int chunk = it*256 + tid;
            int s = chunk >> 4, k = chunk & 15;
            int n = s / 20, w = s - n*20;
            const _Float16* src = grdh +
                ((((size_t)(n*CCH + cc))*GRDH_ROWS + (r0 + w)) << 8) +
                jb + ((k ^ (s & 15)) << 3);
            __builtin_amdgcn_global_load_lds(src, ldsA + chunk*8, 16, 0, 0);
        }
#pragma unroll
        for (int it = 0; it < 9; ++it) {
            int chunk = it*256 + tid;
            int sr = chunk / 72;
            int rest = chunk - sr*72;
            int p = rest / 18, k = rest - p*18;
            const _Float16* src = satp + (size_t)(p & 1)*PCOPY2 +
                (((size_t)((sr & 7)*CCH + cc))*272 + (r0 + (sr >> 3)))*288 +
                jb + 2*(p >> 1) + k*8;
            __builtin_amdgcn_global_load_lds(src,
                (_Float16*)(ldsB + chunk*16), 16, 0, 0);
        }
        asm volatile("s_waitcnt vmcnt(0)" ::: "memory");
        __syncthreads();               // all staging visible

        __builtin_amdgcn_s_setprio(1);   // T5: prefer compute waves over the
        LOADPH(A0, B0, 0);               // co-resident WG's staging waves
#pragma unroll
        for (int ph = 0; ph < 16; ++ph) {
            if ((ph & 1) == 0) {
                if (ph < 15) LOADPH(A1, B1, ph + 1);
                MFMAS(A0, B0);
            } else {
                if (ph < 15) LOADPH(A0, B0, ph + 1);
                MFMAS(A1, B1);
            }
        }
        __builtin_amdgcn_s_setprio(0);
    }
#undef LOADPH
#undef MFMAS

    // Coalesced C-write: stage 68-row halves in (dead) ldsA, then float4 stores.
    float* myp = partials + (size_t)wgid * CORR_N;
    float* ldsOut = (float*)ldsA;      // 40960 >= 68*136*4 = 36992
#pragma unroll
    for (int h = 0; h < 2; ++h) {
        __syncthreads();
#pragma unroll
        for (int a = 0; a < 5; ++a) {
            int rowg0 = (wr*5 + a)*16 + lk*4;
#pragma unroll
            for (int b = 0; b < 5; ++b) {
                int colg = (wc*5 + b)*16 + lrow;
                if (colg < 136) {
#pragma unroll
                    for (int v = 0; v < 4; ++v) {
                        int rl = rowg0 + v - h*68;
                        if (rl >= 0 && rl < 68)
                            ldsOut[rl*136 + colg] = acc[a][b][v];
                    }
                }
            }
        }
        __syncthreads();
#pragma unroll
        for (int it = 0; it < 10; ++it) {
            int idx = it*256 + tid;
            if (idx < 2312) {          // 68 rows x 34 float4
                int row = idx / 34, c4 = idx - row*34;
                *(float4*)(myp + (size_t)(h*68 + row)*136 + c4*4) =
                    *(const float4*)(ldsOut + row*136 + c4*4);
            }
        }
    }
}

// partials (512 slices) -> 8 chunk-partials (no atomics, no init needed)
__global__ __launch_bounds__(256) void k_reduce(const float* __restrict__ partials,
                                                float* __restrict__ corr8) {
    int t = blockIdx.x * 256 + threadIdx.x;
    if (t >= CORR_N) return;
    int w0 = blockIdx.y * 64;
    float s = 0.f;
    for (int w = w0; w < w0 + 64; ++w) s += partials[(size_t)w*CORR_N + t];
    corr8[(size_t)blockIdx.y*CORR_N + t] = s;
}

__global__ __launch_bounds__(256) void k_part(const float* __restrict__ E,
                                              float* __restrict__ partical) {
    int dy = blockIdx.x;   // 0..16
    int m  = blockIdx.y;
    int j  = threadIdx.x;
    int lo = dy - 8; if (lo < 0) lo = 0;
    int hi = dy + 248; if (hi > 256) hi = 256;
    float s = 0.f;
    for (int i = lo; i < hi; ++i) s += E[((size_t)m*256 + i)*256 + j];
    __shared__ float sh[256];
    sh[j] = s;
    __syncthreads();
    if (j < 17) {
        int lo2 = j - 8; if (lo2 < 0) lo2 = 0;
        int hi2 = j + 248; if (hi2 > 256) hi2 = 256;
        float t = 0.f;
        for (int x = lo2; x < hi2; ++x) t += sh[x];
        partical[(m*17 + dy)*17 + j] = t;
    }
}

__global__ __launch_bounds__(64) void k_sim(const float* __restrict__ corr8,
                                            const float* __restrict__ partical,
                                            const float* __restrict__ nsq_part,
                                            float* __restrict__ out,
                                            int* __restrict__ yx,
                                            float* __restrict__ normsqd) {
    int m = blockIdx.x >> 3, n = blockIdx.x & 7;
    int lane = threadIdx.x;
    // Ng from per-row partials (288 values)
    float ns = 0.f;
    for (int r = lane; r < 288; r += 64) ns += nsq_part[n*288 + r];
    for (int o = 32; o; o >>= 1) ns += __shfl_down(ns, o, 64);
    ns = __shfl(ns, 0, 64);
    float Ng = sqrtf(ns);

    float bv = -1e30f; int bpos = 0;
    for (int t = 0; t < 5; ++t) {
        int pos = t*64 + lane;
        if (pos < 289) {
            int dy = pos / 17, dx = pos % 17;
            int idx = (n*17 + dy)*136 + (m*17 + dx);
            float cv = 0.f;
#pragma unroll
            for (int y = 0; y < 8; ++y) cv += corr8[(size_t)y*CORR_N + idx];
            float denom = fmaxf(Ng * sqrtf(partical[(m*17 + dy)*17 + dx]), 1e-12f);
            float val = cv / denom;
            if (val > bv) { bv = val; bpos = pos; }  // strict > keeps first index
        }
    }
    for (int o = 32; o; o >>= 1) {
        float ov = __shfl_xor(bv, o, 64);
        int   op = __shfl_xor(bpos, o, 64);
        if (ov > bv || (ov == bv && op < bpos)) { bv = ov; bpos = op; }
    }
    if (lane == 0) {
        out[m*8 + n] = bv;
        if (m == n) { yx[m] = bpos; normsqd[m] = ns; }
    }
}

__global__ __launch_bounds__(256) void k_mask(const float* __restrict__ csumg,
                                              const float* __restrict__ normsqd,
                                              const int* __restrict__ yx,
                                              float* __restrict__ out) {
    int i = blockIdx.x, m = blockIdx.y, j = threadIdx.x;
    int pos = yx[m];
    int y = pos / 17, x = pos % 17;
    float Ng = sqrtf(normsqd[m]);
    int a = i + 8 - y, b = j + 8 - x;
    float val = 0.f;
    if (a >= 0 && a < 256 && b >= 0 && b < 256)
        val = (fabsf(csumg[((size_t)m*256 + a)*256 + b]) > 1e-6f*Ng) ? 1.f : 0.f;
    out[64 + ((size_t)m*256 + i)*256 + j] = val;
}

extern "C" void kernel_launch(void* const* d_in, const int* in_sizes, int n_in,
                              void* d_out, int out_size, void* d_ws, size_t ws_size,
                              hipStream_t stream) {
    const float* grd = (const float*)d_in[0];
    const float* sat = (const float*)d_in[1];
    float* out = (float*)d_out;
    char* ws = (char*)d_ws;

    float*    normsqd  = (float*)(ws + OFF_NORMSQD);
    int*      yx       = (int*)  (ws + OFF_YX);
    float*    partical = (float*)(ws + OFF_PARTICAL);
    float*    nsq_part = (float*)(ws + OFF_NSQP);
    float*    corr8    = (float*)(ws + OFF_CORR8);
    float*    E        = (float*)(ws + OFF_E);
    float*    csumg    = (float*)(ws + OFF_CSUMG);
    _Float16* grdh     = (_Float16*)(ws + OFF_GRDH);
    _Float16* satp     = (_Float16*)(ws + OFF_SATH);
    float*    partials = (float*)(ws + OFF_PARTIALS);

    hipFuncSetAttribute(reinterpret_cast<const void*>(k_gemm),
                        hipFuncAttributeMaxDynamicSharedMemorySize, LDS_TOTAL);

    k_stage<<<dim3(288, 16), 256, 0, stream>>>(grd, sat, grdh, csumg, nsq_part, satp, E);
    k_gemm<<<NWG_GEMM, 256, LDS_TOTAL, stream>>>(grdh, satp, partials);
    k_reduce<<<dim3((CORR_N + 255)/256, 8), 256, 0, stream>>>(partials, corr8);
    k_part<<<dim3(17, 8), 256, 0, stream>>>(E, partical);
    k_sim<<<64, 64, 0, stream>>>(corr8, partical, nsq_part, out, yx, normsqd);
    k_mask<<<dim3(256, 8), 256, 0, stream>>>(csumg, normsqd, yx, out);
}